// Round 12
// baseline (1980.547 us; speedup 1.0000x reference)
//
#include <hip/hip_runtime.h>
#include <math.h>

typedef __bf16 bf16_t;
typedef bf16_t bf16x8 __attribute__((ext_vector_type(8)));
typedef float  f32x4  __attribute__((ext_vector_type(4)));

#define B_  1024
#define T_  64
#define V_  1024
#define E_  512
#define M_  1024
#define L_  32
#define PE_ 512
#define PO_ 511
#define G3_ 1536
#define M2_ 2048

#define MFMA_BF16 __builtin_amdgcn_mfma_f32_16x16x32_bf16

// async global->LDS: dest = wave-uniform base + lane*16
__device__ __forceinline__ void stage16f(float* lds_base, const float* gsrc) {
  __builtin_amdgcn_global_load_lds(
      (const __attribute__((address_space(1))) unsigned int*)gsrc,
      (__attribute__((address_space(3))) unsigned int*)lds_base, 16, 0, 0);
}

// ---------------------------------------------------------------- prep (fused)
__device__ __forceinline__ void split_chunk(const float* __restrict__ src,
                                            bf16_t* __restrict__ hi,
                                            bf16_t* __restrict__ lo, int blk,
                                            int tid) {
  int i4 = (blk * 256 + tid) * 4;
  float4 v = *(const float4*)&src[i4];
  float vv[4] = {v.x, v.y, v.z, v.w};
#pragma unroll
  for (int j = 0; j < 4; j++) {
    bf16_t h = (bf16_t)vv[j];
    hi[i4 + j] = h;
    lo[i4 + j] = (bf16_t)(vv[j] - (float)h);
  }
}

// Block ranges:
//  [0,512) embed | [512,1280) W_ih | [1280,2304) Wc | [2304,3328) R_real |
//  [3328,4352) R_imag | [4352,4608) W_hh->fragment layout | [4608,4672) Ue |
//  [4672,4736) Uo
// W fragment layout (for gru_nosync direct-to-register B loads):
//   idx = (((c*16+ks)*6+nt)*64+lane)*8 + j  where chunk c in [0,16),
//   k-slice ks in [0,16), n-tile nt in [0,6), lane in [0,64), j in [0,8).
//   element = W_hh[(g*512+e)*512 + k], g=nt>>1, e=c*32+(nt&1)*16+(lane&15),
//   k = ks*32 + (lane>>4)*8 + j.  A wave's (nt) load = contiguous 1 KB.
__global__ __launch_bounds__(256) void prep_all(
    const float* __restrict__ embed, bf16_t* __restrict__ emb_hi,
    bf16_t* __restrict__ emb_lo, const float* __restrict__ W_ih,
    bf16_t* __restrict__ wih_hi, bf16_t* __restrict__ wih_lo,
    const float* __restrict__ Wc, bf16_t* __restrict__ wc_hi,
    bf16_t* __restrict__ wc_lo, const float* __restrict__ R_real,
    bf16_t* __restrict__ rr_hi, bf16_t* __restrict__ rr_lo,
    const float* __restrict__ R_imag, bf16_t* __restrict__ ri_hi,
    bf16_t* __restrict__ ri_lo, const float* __restrict__ W_hh,
    bf16_t* __restrict__ Wfh, bf16_t* __restrict__ Wfl,
    const float* __restrict__ phase, const float* __restrict__ th_e,
    const float* __restrict__ ph_e, const float* __restrict__ rh_e,
    float* __restrict__ Uep, const float* __restrict__ th_o,
    const float* __restrict__ ph_o, const float* __restrict__ rh_o,
    float* __restrict__ Uop) {
  const int bid = blockIdx.x, tid = threadIdx.x;
  if (bid < 512) {
    split_chunk(embed, emb_hi, emb_lo, bid, tid);
  } else if (bid < 1280) {
    split_chunk(W_ih, wih_hi, wih_lo, bid - 512, tid);
  } else if (bid < 2304) {
    split_chunk(Wc, wc_hi, wc_lo, bid - 1280, tid);
  } else if (bid < 3328) {
    split_chunk(R_real, rr_hi, rr_lo, bid - 2304, tid);
  } else if (bid < 4352) {
    split_chunk(R_imag, ri_hi, ri_lo, bid - 3328, tid);
  } else if (bid < 4608) {
    int idx = bid - 4352;           // (c, ks)
    int c = idx >> 4, ks = idx & 15;
    size_t base = ((size_t)(c * 16 + ks) * 6) * 512;
    for (int f = tid; f < 3072; f += 256) {
      int nt = f >> 9, rem = f & 511;
      int lane = rem >> 3, j = rem & 7;
      int l16 = lane & 15, quad = lane >> 4;
      int g = nt >> 1, e = c * 32 + (nt & 1) * 16 + l16;
      int k = ks * 32 + quad * 8 + j;
      float v = W_hh[(size_t)(g * 512 + e) * 512 + k];
      bf16_t h = (bf16_t)v;
      Wfh[base + f] = h;
      Wfl[base + f] = (bf16_t)(v - (float)h);
    }
  } else if (bid < 4672) {
    int idx = (bid - 4608) * 256 + tid;
    if (idx < L_ * PE_) {
      int l = idx >> 9, p = idx & 511;
      float t = th_e[idx], pp = ph_e[idx], r = rh_e[idx];
      float c = cosf(t), s = sinf(t);
      float cp = cosf(pp), sp = sinf(pp), cr = cosf(r), sr = sinf(r);
      float u11r = c * (cp * cr - sp * sr), u11i = c * (cp * sr + sp * cr);
      float u12r = -s * sp, u12i = s * cp;
      float u21r = -s * sr, u21i = s * cr;
      float u22r = c, u22i = 0.0f;
      float f0 = phase[l * M_ + 2 * p], f1 = phase[l * M_ + 2 * p + 1];
      float c0 = cosf(f0), s0 = sinf(f0), c1 = cosf(f1), s1 = sinf(f1);
      float a, b;
      a = u11r * c0 - u11i * s0; b = u11r * s0 + u11i * c0; u11r = a; u11i = b;
      a = u21r * c0 - u21i * s0; b = u21r * s0 + u21i * c0; u21r = a; u21i = b;
      a = u12r * c1 - u12i * s1; b = u12r * s1 + u12i * c1; u12r = a; u12i = b;
      a = u22r * c1 - u22i * s1; b = u22r * s1 + u22i * c1; u22r = a; u22i = b;
      size_t base = (size_t)l * 4096 + (size_t)(p & 7) * 2 * 256 + (p >> 3) * 4;
      *(float4*)&Uep[base]       = make_float4(u11r, u11i, u12r, u12i);
      *(float4*)&Uep[base + 256] = make_float4(u21r, u21i, u22r, u22i);
    }
  } else {
    int idx = (bid - 4672) * 256 + tid;
    if (idx < L_ * PO_) {
      int l = idx / PO_, p = idx % PO_;
      float t = th_o[idx], pp = ph_o[idx], r = rh_o[idx];
      float c = cosf(t), s = sinf(t);
      float cp = cosf(pp), sp = sinf(pp), cr = cosf(r), sr = sinf(r);
      size_t base = (size_t)l * 4096 + (size_t)(p & 7) * 2 * 256 + (p >> 3) * 4;
      *(float4*)&Uop[base] = make_float4(c * (cp * cr - sp * sr),
                                         c * (cp * sr + sp * cr), -s * sp,
                                         s * cp);
      *(float4*)&Uop[base + 256] = make_float4(-s * sr, s * cr, c, 0.0f);
    }
  }
}

// ---------------------------------------------------------------- generic split GEMM
__global__ __launch_bounds__(256) void gemm_bt_mfma_split(
    const bf16_t* __restrict__ Ah, const bf16_t* __restrict__ Al,
    const bf16_t* __restrict__ Bh, const bf16_t* __restrict__ Bl,
    float* __restrict__ C, int Ndim, int K) {
  __shared__ bf16_t sAh[64 * 32], sAl[64 * 32], sBh[64 * 32], sBl[64 * 32];
  const int tid = threadIdx.x;
  const int m0 = blockIdx.y * 64, n0 = blockIdx.x * 64;
  const int wave = tid >> 6, lane = tid & 63;
  const int wr = wave >> 1, wc = wave & 1;
  const int quad = lane >> 4, l16 = lane & 15;
  f32x4 acc[2][2] = {};
  const int srow = tid >> 2, sk = (tid & 3) * 8;

  for (int k0 = 0; k0 < K; k0 += 32) {
    bf16x8 ah = *(const bf16x8*)&Ah[(size_t)(m0 + srow) * K + k0 + sk];
    bf16x8 al = *(const bf16x8*)&Al[(size_t)(m0 + srow) * K + k0 + sk];
    bf16x8 bh = *(const bf16x8*)&Bh[(size_t)(n0 + srow) * K + k0 + sk];
    bf16x8 bl = *(const bf16x8*)&Bl[(size_t)(n0 + srow) * K + k0 + sk];
    __syncthreads();
    *(bf16x8*)&sAh[srow * 32 + sk] = ah;
    *(bf16x8*)&sAl[srow * 32 + sk] = al;
    *(bf16x8*)&sBh[srow * 32 + sk] = bh;
    *(bf16x8*)&sBl[srow * 32 + sk] = bl;
    __syncthreads();
    bf16x8 fAh[2], fAl[2], fBh[2], fBl[2];
#pragma unroll
    for (int i = 0; i < 2; i++) {
      fAh[i] = *(const bf16x8*)&sAh[(wr * 32 + i * 16 + l16) * 32 + quad * 8];
      fAl[i] = *(const bf16x8*)&sAl[(wr * 32 + i * 16 + l16) * 32 + quad * 8];
      fBh[i] = *(const bf16x8*)&sBh[(wc * 32 + i * 16 + l16) * 32 + quad * 8];
      fBl[i] = *(const bf16x8*)&sBl[(wc * 32 + i * 16 + l16) * 32 + quad * 8];
    }
#pragma unroll
    for (int i = 0; i < 2; i++)
#pragma unroll
      for (int j = 0; j < 2; j++) {
        acc[i][j] = MFMA_BF16(fAh[i], fBh[j], acc[i][j], 0, 0, 0);
        acc[i][j] = MFMA_BF16(fAh[i], fBl[j], acc[i][j], 0, 0, 0);
        acc[i][j] = MFMA_BF16(fAl[i], fBh[j], acc[i][j], 0, 0, 0);
      }
  }
#pragma unroll
  for (int i = 0; i < 2; i++)
#pragma unroll
    for (int j = 0; j < 2; j++)
#pragma unroll
      for (int r = 0; r < 4; r++) {
        int row = wr * 32 + i * 16 + quad * 4 + r;
        int col = wc * 32 + j * 16 + l16;
        C[(size_t)(m0 + row) * Ndim + n0 + col] = acc[i][j][r];
      }
}

// ---------------------------------------------------------------- GRU: no-sync persistent
// KEY: GRU rows are batch-independent. Block owns 16 batch rows COMPLETELY
// (all 512 e-dims) -> runs all 64 timesteps with h in LDS, ONE plain launch,
// one __syncthreads per step, ZERO cross-block traffic. 64 blocks; W read
// via fragment-contiguous layout (coalesced 1KB bursts, L2-resident, no
// K-loop barriers so latency pipelines freely).
#define HP_ 520  // h LDS pitch (breaks ds_read_b128 bank aliasing vs 512)

__global__ __launch_bounds__(512, 1) void gru_nosync(
    const bf16_t* __restrict__ Wfh, const bf16_t* __restrict__ Wfl,
    const int* __restrict__ tok, const float* __restrict__ eg,
    const float* __restrict__ b_ih, const float* __restrict__ b_hh,
    bf16_t* __restrict__ Hout_hi, bf16_t* __restrict__ Hout_lo) {
  __shared__ bf16_t sHh[2][16 * HP_], sHl[2][16 * HP_];
  __shared__ float sbih[G3_], sbhh[G3_];
  const int tid = threadIdx.x;
  const int bt16 = blockIdx.x * 16;  // batch-row base
  const int wave = tid >> 6, lane = tid & 63;
  const int l16 = lane & 15, quad = lane >> 4;

  // init: biases to LDS, zero h buffer 0
  for (int i = tid; i < G3_; i += 512) {
    sbih[i] = b_ih[i];
    sbhh[i] = b_hh[i];
  }
  for (int i = tid; i < 16 * HP_; i += 512) {
    sHh[0][i] = (bf16_t)0.0f;
    sHl[0][i] = (bf16_t)0.0f;
  }
  __syncthreads();

#pragma unroll 1
  for (int t = 0; t < T_; ++t) {
    const int cur = t & 1, nxt = cur ^ 1;
#pragma unroll 1
    for (int cc = 0; cc < 2; ++cc) {
      const int ci = wave * 2 + cc;  // e-chunk [ci*32, ci*32+32)
      // epilogue prefetch (independent of GEMM): tokens + eg gather
      int tkr[4];
#pragma unroll
      for (int r = 0; r < 4; ++r)
        tkr[r] = tok[(bt16 + quad * 4 + r) * T_ + t];
      float egv[3][8];  // [gate][half*4+r]
#pragma unroll
      for (int half = 0; half < 2; ++half) {
        int e = ci * 32 + half * 16 + l16;
#pragma unroll
        for (int r = 0; r < 4; ++r)
#pragma unroll
          for (int g = 0; g < 3; ++g)
            egv[g][half * 4 + r] = eg[(size_t)tkr[r] * G3_ + g * 512 + e];
      }
      // GEMM: 16 rows x 96 cols (6 n-tiles: g0e0,g0e1,g1e0,g1e1,g2e0,g2e1)
      f32x4 acc[6] = {};
      const bf16_t* wbh = Wfh + ((size_t)(ci * 16) * 6) * 512 + lane * 8;
      const bf16_t* wbl = Wfl + ((size_t)(ci * 16) * 6) * 512 + lane * 8;
      bf16x8 wh[6], wl[6];
#pragma unroll
      for (int nt = 0; nt < 6; ++nt) {
        wh[nt] = *(const bf16x8*)(wbh + nt * 512);
        wl[nt] = *(const bf16x8*)(wbl + nt * 512);
      }
#pragma unroll 1
      for (int ks = 0; ks < 16; ++ks) {
        bf16x8 ah = *(const bf16x8*)&sHh[cur][l16 * HP_ + ks * 32 + quad * 8];
        bf16x8 al = *(const bf16x8*)&sHl[cur][l16 * HP_ + ks * 32 + quad * 8];
        bf16x8 nwh[6], nwl[6];
        if (ks < 15) {
          const bf16_t* nh = wbh + (size_t)(ks + 1) * 6 * 512;
          const bf16_t* nl = wbl + (size_t)(ks + 1) * 6 * 512;
#pragma unroll
          for (int nt = 0; nt < 6; ++nt) {
            nwh[nt] = *(const bf16x8*)(nh + nt * 512);
            nwl[nt] = *(const bf16x8*)(nl + nt * 512);
          }
        }
        // product-outer order: 6 independent acc chains between reuses
#pragma unroll
        for (int nt = 0; nt < 6; ++nt) acc[nt] = MFMA_BF16(ah, wh[nt], acc[nt], 0, 0, 0);
#pragma unroll
        for (int nt = 0; nt < 6; ++nt) acc[nt] = MFMA_BF16(ah, wl[nt], acc[nt], 0, 0, 0);
#pragma unroll
        for (int nt = 0; nt < 6; ++nt) acc[nt] = MFMA_BF16(al, wh[nt], acc[nt], 0, 0, 0);
        if (ks < 15) {
#pragma unroll
          for (int nt = 0; nt < 6; ++nt) { wh[nt] = nwh[nt]; wl[nt] = nwl[nt]; }
        }
      }
      // epilogue: C layout row=quad*4+r, col=l16; gates at nt = g*2 + half
#pragma unroll
      for (int half = 0; half < 2; ++half) {
        int e = ci * 32 + half * 16 + l16;
#pragma unroll
        for (int r = 0; r < 4; ++r) {
          int row = quad * 4 + r;
          float hr = acc[0 + half][r] + sbhh[e];
          float hz = acc[2 + half][r] + sbhh[512 + e];
          float hn = acc[4 + half][r] + sbhh[1024 + e];
          float ir = egv[0][half * 4 + r] + sbih[e];
          float iz = egv[1][half * 4 + r] + sbih[512 + e];
          float in_ = egv[2][half * 4 + r] + sbih[1024 + e];
          float rg = 1.0f / (1.0f + __expf(-(ir + hr)));
          float z = 1.0f / (1.0f + __expf(-(iz + hz)));
          float targ = fminf(fmaxf(in_ + rg * hn, -15.0f), 15.0f);
          float e2 = __expf(2.0f * targ);
          float n = (e2 - 1.0f) / (e2 + 1.0f);
          float hv = (float)sHh[cur][row * HP_ + e] + (float)sHl[cur][row * HP_ + e];
          float hnew = (1.0f - z) * n + z * hv;
          bf16_t hh = (bf16_t)hnew;
          sHh[nxt][row * HP_ + e] = hh;
          sHl[nxt][row * HP_ + e] = (bf16_t)(hnew - (float)hh);
        }
      }
    }
    __syncthreads();  // all e-chunks of h(t+1) visible before next step
  }
  // final h is in buffer 0 (t=63: cur=1 -> wrote nxt=0); write to global
  for (int f = tid; f < 16 * 512; f += 512) {
    int row = f >> 9, e = f & 511;
    size_t g = (size_t)(bt16 + row) * 512 + e;
    Hout_hi[g] = sHh[0][row * HP_ + e];
    Hout_lo[g] = sHl[0][row * HP_ + e];
  }
}

// ---------------------------------------------------------------- MZI core (qc4, best)
__device__ inline void apply_u(float4 A, float4 Bv, float& x0r, float& x0i,
                               float& x1r, float& x1i) {
  float n0r = A.x * x0r - A.y * x0i + A.z * x1r - A.w * x1i;
  float n0i = A.x * x0i + A.y * x0r + A.z * x1i + A.w * x1r;
  float n1r = Bv.x * x0r - Bv.y * x0i + Bv.z * x1r - Bv.w * x1i;
  float n1i = Bv.x * x0i + Bv.y * x0r + Bv.z * x1i + Bv.w * x1r;
  x0r = n0r; x0i = n0i; x1r = n1r; x1i = n1i;
}

__global__ __launch_bounds__(256) void qc4(
    const float* __restrict__ zc, const float* __restrict__ bc,
    const float* __restrict__ Uep, const float* __restrict__ Uop,
    bf16_t* __restrict__ prh, bf16_t* __restrict__ prl,
    bf16_t* __restrict__ pih, bf16_t* __restrict__ pil) {
  __shared__ float sU[2][8192];
  const int tid = threadIdx.x;
  const int wave = tid >> 6, lane = tid & 63;
  const int b = blockIdx.x * 4 + wave;
  const int e0 = lane * 16;

#define STAGE_LAYER(l, buf)                                                  \
  {                                                                          \
    _Pragma("unroll") for (int r = 0; r < 4; r++) {                          \
      stage16f(&sU[buf][r * 1024 + wave * 256],                              \
               &Uep[(size_t)(l) * 4096 + r * 1024 + wave * 256 + lane * 4]); \
      stage16f(&sU[buf][4096 + r * 1024 + wave * 256],                       \
               &Uop[(size_t)(l) * 4096 + r * 1024 + wave * 256 + lane * 4]); \
    }                                                                        \
  }

  float xr[16], xi[16];
  {
    const float4* zr4 = (const float4*)&zc[(size_t)b * M2_ + e0];
    const float4* zi4 = (const float4*)&zc[(size_t)b * M2_ + M_ + e0];
    const float4* br4 = (const float4*)&bc[e0];
    const float4* bi4 = (const float4*)&bc[M_ + e0];
#pragma unroll
    for (int q = 0; q < 4; q++) {
      float4 a = zr4[q], bb = br4[q];
      xr[4 * q + 0] = a.x + bb.x; xr[4 * q + 1] = a.y + bb.y;
      xr[4 * q + 2] = a.z + bb.z; xr[4 * q + 3] = a.w + bb.w;
      float4 c = zi4[q], d = bi4[q];
      xi[4 * q + 0] = c.x + d.x; xi[4 * q + 1] = c.y + d.y;
      xi[4 * q + 2] = c.z + d.z; xi[4 * q + 3] = c.w + d.w;
    }
  }
  STAGE_LAYER(0, 0);
  {
    float s = 0.0f;
#pragma unroll
    for (int k = 0; k < 16; k++) s += xr[k] * xr[k] + xi[k] * xi[k];
    for (int off = 32; off; off >>= 1) s += __shfl_xor(s, off);
    float inv = 1.0f / sqrtf(s + 1e-8f);
#pragma unroll
    for (int k = 0; k < 16; k++) { xr[k] *= inv; xi[k] *= inv; }
  }
  __syncthreads();

#pragma unroll 1
  for (int l = 0; l < L_; ++l) {
    const int buf = l & 1;
    if (l + 1 < L_) STAGE_LAYER(l + 1, 1 - buf);
    const float* Ub = &sU[buf][0];
    const float* Ob = &sU[buf][4096];
    float4 eu[16];
#pragma unroll
    for (int j = 0; j < 16; j++) eu[j] = *(const float4*)&Ub[j * 256 + lane * 4];
#pragma unroll
    for (int j = 0; j < 8; j++)
      apply_u(eu[2 * j], eu[2 * j + 1], xr[2 * j], xi[2 * j], xr[2 * j + 1],
              xi[2 * j + 1]);
    float nr = __shfl_down(xr[0], 1);
    float ni = __shfl_down(xi[0], 1);
    float4 ou[16];
#pragma unroll
    for (int j = 0; j < 16; j++) ou[j] = *(const float4*)&Ob[j * 256 + lane * 4];
#pragma unroll
    for (int j = 0; j < 7; j++)
      apply_u(ou[2 * j], ou[2 * j + 1], xr[2 * j + 1], xi[2 * j + 1],
              xr[2 * j + 2], xi[2 * j + 2]);
    float sr_ = 0.0f, si_ = 0.0f;
    if (lane < 63) {
      float4 A = ou[14], Bv = ou[15];
      float n0r = A.x * xr[15] - A.y * xi[15] + A.z * nr - A.w * ni;
      float n0i = A.x * xi[15] + A.y * xr[15] + A.z * ni + A.w * nr;
      sr_ = Bv.x * xr[15] - Bv.y * xi[15] + Bv.z * nr - Bv.w * ni;
      si_ = Bv.x * xi[15] + Bv.y * xr[15] + Bv.z * ni + Bv.w * nr;
      xr[15] = n0r; xi[15] = n0i;
    }
    float rr = __shfl_up(sr_, 1);
    float ri2 = __shfl_up(si_, 1);
    if (lane > 0) { xr[0] = rr; xi[0] = ri2; }
    __syncthreads();
  }
#undef STAGE_LAYER
  size_t base = (size_t)b * M_ + e0;
#pragma unroll
  for (int half = 0; half < 2; half++) {
    bf16x8 vh, vl, wh, wl;
#pragma unroll
    for (int k = 0; k < 8; k++) {
      float vr = xr[half * 8 + k], vi = xi[half * 8 + k];
      bf16_t h1 = (bf16_t)vr;
      vh[k] = h1; vl[k] = (bf16_t)(vr - (float)h1);
      bf16_t h2 = (bf16_t)vi;
      wh[k] = h2; wl[k] = (bf16_t)(vi - (float)h2);
    }
    *(bf16x8*)&prh[base + half * 8] = vh;
    *(bf16x8*)&prl[base + half * 8] = vl;
    *(bf16x8*)&pih[base + half * 8] = wh;
    *(bf16x8*)&pil[base + half * 8] = wl;
  }
}

// ---------------------------------------------------------------- readout
__global__ __launch_bounds__(256) void readout_mfma(
    const bf16_t* __restrict__ Arh, const bf16_t* __restrict__ Arl,
    const bf16_t* __restrict__ Aih, const bf16_t* __restrict__ Ail,
    const bf16_t* __restrict__ Brh, const bf16_t* __restrict__ Brl,
    const bf16_t* __restrict__ Bih, const bf16_t* __restrict__ Bil,
    float* __restrict__ out) {
  __shared__ bf16_t sArh[64 * 32], sArl[64 * 32], sAih[64 * 32], sAil[64 * 32];
  __shared__ bf16_t sBrh[64 * 32], sBrl[64 * 32], sBih[64 * 32], sBil[64 * 32];
  const int tid = threadIdx.x;
  const int b0 = blockIdx.y * 64, v0 = blockIdx.x * 64;
  const int wave = tid >> 6, lane = tid & 63;
  const int wr = wave >> 1, wc = wave & 1;
  const int quad = lane >> 4, l16 = lane & 15;
  f32x4 aP[2][2] = {}, aQ[2][2] = {}, aI[2][2] = {};
  const int srow = tid >> 2, sk = (tid & 3) * 8;

  for (int k0 = 0; k0 < M_; k0 += 32) {
    size_t aoff = (size_t)(b0 + srow) * M_ + k0 + sk;
    size_t boff = (size_t)(v0 + srow) * M_ + k0 + sk;
    bf16x8 v0r = *(const bf16x8*)&Arh[aoff];
    bf16x8 v1r = *(const bf16x8*)&Arl[aoff];
    bf16x8 v2r = *(const bf16x8*)&Aih[aoff];
    bf16x8 v3r = *(const bf16x8*)&Ail[aoff];
    bf16x8 v4r = *(const bf16x8*)&Brh[boff];
    bf16x8 v5r = *(const bf16x8*)&Brl[boff];
    bf16x8 v6r = *(const bf16x8*)&Bih[boff];
    bf16x8 v7r = *(const bf16x8*)&Bil[boff];
    __syncthreads();
    *(bf16x8*)&sArh[srow * 32 + sk] = v0r;
    *(bf16x8*)&sArl[srow * 32 + sk] = v1r;
    *(bf16x8*)&sAih[srow * 32 + sk] = v2r;
    *(bf16x8*)&sAil[srow * 32 + sk] = v3r;
    *(bf16x8*)&sBrh[srow * 32 + sk] = v4r;
    *(bf16x8*)&sBrl[srow * 32 + sk] = v5r;
    *(bf16x8*)&sBih[srow * 32 + sk] = v6r;
    *(bf16x8*)&sBil[srow * 32 + sk] = v7r;
    __syncthreads();
    bf16x8 fArh[2], fArl[2], fAih[2], fAil[2], fBrh[2], fBrl[2], fBih[2], fBil[2];
#pragma unroll
    for (int i = 0; i < 2; i++) {
      int ra = (wr * 32 + i * 16 + l16) * 32 + quad * 8;
      int rb = (wc * 32 + i * 16 + l16) * 32 + quad * 8;
      fArh[i] = *(const bf16x8*)&sArh[ra];
      fArl[i] = *(const bf16x8*)&sArl[ra];
      fAih[i] = *(const bf16x8*)&sAih[ra];
      fAil[i] = *(const bf16x8*)&sAil[ra];
      fBrh[i] = *(const bf16x8*)&sBrh[rb];
      fBrl[i] = *(const bf16x8*)&sBrl[rb];
      fBih[i] = *(const bf16x8*)&sBih[rb];
      fBil[i] = *(const bf16x8*)&sBil[rb];
    }
#pragma unroll
    for (int i = 0; i < 2; i++)
#pragma unroll
      for (int j = 0; j < 2; j++) {
        aP[i][j] = MFMA_BF16(fArh[i], fBrh[j], aP[i][j], 0, 0, 0);
        aP[i][j] = MFMA_BF16(fArh[i], fBrl[j], aP[i][j], 0, 0, 0);
        aP[i][j] = MFMA_BF16(fArl[i], fBrh[j], aP[i][j], 0, 0, 0);
        aQ[i][j] = MFMA_BF16(fAih[i], fBih[j], aQ[i][j], 0, 0, 0);
        aQ[i][j] = MFMA_BF16(fAih[i], fBil[j], aQ[i][j], 0, 0, 0);
        aQ[i][j] = MFMA_BF16(fAil[i], fBih[j], aQ[i][j], 0, 0, 0);
        aI[i][j] = MFMA_BF16(fArh[i], fBih[j], aI[i][j], 0, 0, 0);
        aI[i][j] = MFMA_BF16(fArh[i], fBil[j], aI[i][j], 0, 0, 0);
        aI[i][j] = MFMA_BF16(fArl[i], fBih[j], aI[i][j], 0, 0, 0);
        aI[i][j] = MFMA_BF16(fAih[i], fBrh[j], aI[i][j], 0, 0, 0);
        aI[i][j] = MFMA_BF16(fAih[i], fBrl[j], aI[i][j], 0, 0, 0);
        aI[i][j] = MFMA_BF16(fAil[i], fBrh[j], aI[i][j], 0, 0, 0);
      }
  }
#pragma unroll
  for (int i = 0; i < 2; i++)
#pragma unroll
    for (int j = 0; j < 2; j++)
#pragma unroll
      for (int r = 0; r < 4; r++) {
        int row = wr * 32 + i * 16 + quad * 4 + r;
        int col = wc * 32 + j * 16 + l16;
        float re = aP[i][j][r] - aQ[i][j][r];
        float im = aI[i][j][r];
        out[(size_t)(b0 + row) * V_ + v0 + col] = logf(re * re + im * im + 1e-12f);
      }
}

// ---------------------------------------------------------------- logsumexp
__global__ __launch_bounds__(256) void lse_kernel(float* __restrict__ out) {
  __shared__ float redm[4], reds[4];
  const int b = blockIdx.x, t = threadIdx.x;
  float4 v = *(float4*)&out[(size_t)b * V_ + 4 * t];
  float mx = fmaxf(fmaxf(v.x, v.y), fmaxf(v.z, v.w));
  for (int off = 32; off; off >>= 1) mx = fmaxf(mx, __shfl_down(mx, off, 64));
  if ((t & 63) == 0) redm[t >> 6] = mx;
  __syncthreads();
  mx = fmaxf(fmaxf(redm[0], redm[1]), fmaxf(redm[2], redm[3]));
  float s = expf(v.x - mx) + expf(v.y - mx) + expf(v.z - mx) + expf(v.w - mx);
  for (int off = 32; off; off >>= 1) s += __shfl_down(s, off, 64);
  if ((t & 63) == 0) reds[t >> 6] = s;
  __syncthreads();
  s = reds[0] + reds[1] + reds[2] + reds[3];
  float lse = mx + logf(s);
  v.x -= lse; v.y -= lse; v.z -= lse; v.w -= lse;
  *(float4*)&out[(size_t)b * V_ + 4 * t] = v;
}

// ---------------------------------------------------------------- launch
extern "C" void kernel_launch(void* const* d_in, const int* in_sizes, int n_in,
                              void* d_out, int out_size, void* d_ws, size_t ws_size,
                              hipStream_t stream) {
  const int*   tokens = (const int*)d_in[0];
  const float* embed  = (const float*)d_in[1];
  const float* W_ih   = (const float*)d_in[2];
  const float* W_hh   = (const float*)d_in[3];
  const float* b_ih   = (const float*)d_in[4];
  const float* b_hh   = (const float*)d_in[5];
  const float* Wc     = (const float*)d_in[6];
  const float* bc     = (const float*)d_in[7];
  const float* phase  = (const float*)d_in[8];
  const float* theta_e = (const float*)d_in[9];
  const float* phi_e  = (const float*)d_in[10];
  const float* rho_e  = (const float*)d_in[11];
  const float* theta_o = (const float*)d_in[12];
  const float* phi_o  = (const float*)d_in[13];
  const float* rho_o  = (const float*)d_in[14];
  const float* R_real = (const float*)d_in[15];
  const float* R_imag = (const float*)d_in[16];
  float* out = (float*)d_out;

  char* w = (char*)d_ws;
  auto alloc = [&](size_t bytes) -> void* {
    void* p = (void*)w;
    w += (bytes + 255) & ~(size_t)255;
    return p;
  };
  // region0: weight splits; later aliased by psi hi/lo (dead by then)
  char* region0 = w;
  bf16_t* emb_hi = (bf16_t*)alloc((size_t)V_ * E_ * 2);
  bf16_t* emb_lo = (bf16_t*)alloc((size_t)V_ * E_ * 2);
  bf16_t* wih_hi = (bf16_t*)alloc((size_t)G3_ * E_ * 2);
  bf16_t* wih_lo = (bf16_t*)alloc((size_t)G3_ * E_ * 2);
  bf16_t* wc_hi  = (bf16_t*)alloc((size_t)M2_ * E_ * 2);
  bf16_t* wc_lo  = (bf16_t*)alloc((size_t)M2_ * E_ * 2);
  // region1: eg + Wfrag; later aliased by zc
  char* region1 = w;
  float*  eg   = (float*)alloc((size_t)V_ * G3_ * 4);
  bf16_t* Wfh  = (bf16_t*)alloc((size_t)G3_ * E_ * 2);
  bf16_t* Wfl  = (bf16_t*)alloc((size_t)G3_ * E_ * 2);
  // persistent
  bf16_t* h0_hi = (bf16_t*)alloc((size_t)B_ * E_ * 2);
  bf16_t* h0_lo = (bf16_t*)alloc((size_t)B_ * E_ * 2);
  bf16_t* rr_hi = (bf16_t*)alloc((size_t)V_ * M_ * 2);
  bf16_t* rr_lo = (bf16_t*)alloc((size_t)V_ * M_ * 2);
  bf16_t* ri_hi = (bf16_t*)alloc((size_t)V_ * M_ * 2);
  bf16_t* ri_lo = (bf16_t*)alloc((size_t)V_ * M_ * 2);
  float*  Uep   = (float*)alloc((size_t)L_ * 4096 * 4);
  float*  Uop   = (float*)alloc((size_t)L_ * 4096 * 4);

  // aliases
  float*  zc  = (float*)region1;
  bf16_t* prh = (bf16_t*)(region0 + 0 * 2097152);
  bf16_t* prl = (bf16_t*)(region0 + 1 * 2097152);
  bf16_t* pih = (bf16_t*)(region0 + 2 * 2097152);
  bf16_t* pil = (bf16_t*)(region0 + 3 * 2097152);

  // ONE fused prep launch
  prep_all<<<4736, 256, 0, stream>>>(
      embed, emb_hi, emb_lo, W_ih, wih_hi, wih_lo, Wc, wc_hi, wc_lo, R_real,
      rr_hi, rr_lo, R_imag, ri_hi, ri_lo, W_hh, Wfh, Wfl, phase, theta_e,
      phi_e, rho_e, Uep, theta_o, phi_o, rho_o, Uop);

  // eg = embed @ W_ih^T  (V x 3E)
  {
    dim3 grid(G3_ / 64, V_ / 64);
    gemm_bt_mfma_split<<<grid, 256, 0, stream>>>(emb_hi, emb_lo, wih_hi, wih_lo,
                                                 eg, G3_, E_);
  }

  // GRU: ONE launch, all 64 steps, zero cross-block communication
  // (batch rows are independent; each block owns 16 rows end-to-end)
  gru_nosync<<<64, 512, 0, stream>>>(Wfh, Wfl, tokens, eg, b_ih, b_hh,
                                     h0_hi, h0_lo);

  // zc = h @ Wc^T  (B x 2M)
  {
    dim3 grid(M2_ / 64, B_ / 64);
    gemm_bt_mfma_split<<<grid, 256, 0, stream>>>(h0_hi, h0_lo, wc_hi, wc_lo,
                                                 zc, M2_, E_);
  }

  // MZI stack (qc4: dbuf LDS tables — best measured variant)
  qc4<<<B_ / 4, 256, 0, stream>>>(zc, bc, Uep, Uop, prh, prl, pih, pil);

  // readout
  {
    dim3 grid(V_ / 64, B_ / 64);
    readout_mfma<<<grid, 256, 0, stream>>>(prh, prl, pih, pil, rr_hi, rr_lo,
                                           ri_hi, ri_lo, out);
  }

  // logsumexp
  lse_kernel<<<B_, 256, 0, stream>>>(out);
}

// Round 13
// 1048.496 us; speedup vs baseline: 1.8889x; 1.8889x over previous
//
#include <hip/hip_runtime.h>
#include <math.h>

typedef __bf16 bf16_t;
typedef bf16_t bf16x8 __attribute__((ext_vector_type(8)));
typedef float  f32x4  __attribute__((ext_vector_type(4)));

#define B_  1024
#define T_  64
#define V_  1024
#define E_  512
#define M_  1024
#define L_  32
#define PE_ 512
#define PO_ 511
#define G3_ 1536
#define M2_ 2048

#define MFMA_BF16 __builtin_amdgcn_mfma_f32_16x16x32_bf16

// async global->LDS: dest = wave-uniform base + lane*16
__device__ __forceinline__ void stage16f(float* lds_base, const float* gsrc) {
  __builtin_amdgcn_global_load_lds(
      (const __attribute__((address_space(1))) unsigned int*)gsrc,
      (__attribute__((address_space(3))) unsigned int*)lds_base, 16, 0, 0);
}

// ---------------------------------------------------------------- prep (fused)
__device__ __forceinline__ void split_chunk(const float* __restrict__ src,
                                            bf16_t* __restrict__ hi,
                                            bf16_t* __restrict__ lo, int blk,
                                            int tid) {
  int i4 = (blk * 256 + tid) * 4;
  float4 v = *(const float4*)&src[i4];
  float vv[4] = {v.x, v.y, v.z, v.w};
#pragma unroll
  for (int j = 0; j < 4; j++) {
    bf16_t h = (bf16_t)vv[j];
    hi[i4 + j] = h;
    lo[i4 + j] = (bf16_t)(vv[j] - (float)h);
  }
}

// Block ranges:
//  [0,512) embed | [512,1280) W_ih | [1280,2304) Wc | [2304,3328) R_real |
//  [3328,4352) R_imag | [4352,5888) permute W_hh (Wp rows q=c*96+g*32+e_l) |
//  [5888,5952) Ue | [5952,6016) Uo
__global__ __launch_bounds__(256) void prep_all(
    const float* __restrict__ embed, bf16_t* __restrict__ emb_hi,
    bf16_t* __restrict__ emb_lo, const float* __restrict__ W_ih,
    bf16_t* __restrict__ wih_hi, bf16_t* __restrict__ wih_lo,
    const float* __restrict__ Wc, bf16_t* __restrict__ wc_hi,
    bf16_t* __restrict__ wc_lo, const float* __restrict__ R_real,
    bf16_t* __restrict__ rr_hi, bf16_t* __restrict__ rr_lo,
    const float* __restrict__ R_imag, bf16_t* __restrict__ ri_hi,
    bf16_t* __restrict__ ri_lo, const float* __restrict__ W_hh,
    bf16_t* __restrict__ Wp_hi, bf16_t* __restrict__ Wp_lo,
    const float* __restrict__ phase, const float* __restrict__ th_e,
    const float* __restrict__ ph_e, const float* __restrict__ rh_e,
    float* __restrict__ Uep, const float* __restrict__ th_o,
    const float* __restrict__ ph_o, const float* __restrict__ rh_o,
    float* __restrict__ Uop) {
  const int bid = blockIdx.x, tid = threadIdx.x;
  if (bid < 512) {
    split_chunk(embed, emb_hi, emb_lo, bid, tid);
  } else if (bid < 1280) {
    split_chunk(W_ih, wih_hi, wih_lo, bid - 512, tid);
  } else if (bid < 2304) {
    split_chunk(Wc, wc_hi, wc_lo, bid - 1280, tid);
  } else if (bid < 3328) {
    split_chunk(R_real, rr_hi, rr_lo, bid - 2304, tid);
  } else if (bid < 4352) {
    split_chunk(R_imag, ri_hi, ri_lo, bid - 3328, tid);
  } else if (bid < 5888) {
    int q = bid - 4352;  // permuted row: q = c*96 + g*32 + e_l
    int c = q / 96, loc = q % 96;
    int g = loc >> 5, el = loc & 31;
    const float* src = &W_hh[(size_t)(g * 512 + c * 32 + el) * 512];
    bf16_t* dh = &Wp_hi[(size_t)q * 512];
    bf16_t* dl = &Wp_lo[(size_t)q * 512];
    for (int k = tid; k < 512; k += 256) {
      float v = src[k];
      bf16_t h = (bf16_t)v;
      dh[k] = h;
      dl[k] = (bf16_t)(v - (float)h);
    }
  } else if (bid < 5952) {
    int idx = (bid - 5888) * 256 + tid;
    if (idx < L_ * PE_) {
      int l = idx >> 9, p = idx & 511;
      float t = th_e[idx], pp = ph_e[idx], r = rh_e[idx];
      float c = cosf(t), s = sinf(t);
      float cp = cosf(pp), sp = sinf(pp), cr = cosf(r), sr = sinf(r);
      float u11r = c * (cp * cr - sp * sr), u11i = c * (cp * sr + sp * cr);
      float u12r = -s * sp, u12i = s * cp;
      float u21r = -s * sr, u21i = s * cr;
      float u22r = c, u22i = 0.0f;
      float f0 = phase[l * M_ + 2 * p], f1 = phase[l * M_ + 2 * p + 1];
      float c0 = cosf(f0), s0 = sinf(f0), c1 = cosf(f1), s1 = sinf(f1);
      float a, b;
      a = u11r * c0 - u11i * s0; b = u11r * s0 + u11i * c0; u11r = a; u11i = b;
      a = u21r * c0 - u21i * s0; b = u21r * s0 + u21i * c0; u21r = a; u21i = b;
      a = u12r * c1 - u12i * s1; b = u12r * s1 + u12i * c1; u12r = a; u12i = b;
      a = u22r * c1 - u22i * s1; b = u22r * s1 + u22i * c1; u22r = a; u22i = b;
      size_t base = (size_t)l * 4096 + (size_t)(p & 7) * 2 * 256 + (p >> 3) * 4;
      *(float4*)&Uep[base]       = make_float4(u11r, u11i, u12r, u12i);
      *(float4*)&Uep[base + 256] = make_float4(u21r, u21i, u22r, u22i);
    }
  } else {
    int idx = (bid - 5952) * 256 + tid;
    if (idx < L_ * PO_) {
      int l = idx / PO_, p = idx % PO_;
      float t = th_o[idx], pp = ph_o[idx], r = rh_o[idx];
      float c = cosf(t), s = sinf(t);
      float cp = cosf(pp), sp = sinf(pp), cr = cosf(r), sr = sinf(r);
      size_t base = (size_t)l * 4096 + (size_t)(p & 7) * 2 * 256 + (p >> 3) * 4;
      *(float4*)&Uop[base] = make_float4(c * (cp * cr - sp * sr),
                                         c * (cp * sr + sp * cr), -s * sp,
                                         s * cp);
      *(float4*)&Uop[base + 256] = make_float4(-s * sr, s * cr, c, 0.0f);
    }
  }
}

// ---------------------------------------------------------------- generic split GEMM
__global__ __launch_bounds__(256) void gemm_bt_mfma_split(
    const bf16_t* __restrict__ Ah, const bf16_t* __restrict__ Al,
    const bf16_t* __restrict__ Bh, const bf16_t* __restrict__ Bl,
    float* __restrict__ C, int Ndim, int K) {
  __shared__ bf16_t sAh[64 * 32], sAl[64 * 32], sBh[64 * 32], sBl[64 * 32];
  const int tid = threadIdx.x;
  const int m0 = blockIdx.y * 64, n0 = blockIdx.x * 64;
  const int wave = tid >> 6, lane = tid & 63;
  const int wr = wave >> 1, wc = wave & 1;
  const int quad = lane >> 4, l16 = lane & 15;
  f32x4 acc[2][2] = {};
  const int srow = tid >> 2, sk = (tid & 3) * 8;

  for (int k0 = 0; k0 < K; k0 += 32) {
    bf16x8 ah = *(const bf16x8*)&Ah[(size_t)(m0 + srow) * K + k0 + sk];
    bf16x8 al = *(const bf16x8*)&Al[(size_t)(m0 + srow) * K + k0 + sk];
    bf16x8 bh = *(const bf16x8*)&Bh[(size_t)(n0 + srow) * K + k0 + sk];
    bf16x8 bl = *(const bf16x8*)&Bl[(size_t)(n0 + srow) * K + k0 + sk];
    __syncthreads();
    *(bf16x8*)&sAh[srow * 32 + sk] = ah;
    *(bf16x8*)&sAl[srow * 32 + sk] = al;
    *(bf16x8*)&sBh[srow * 32 + sk] = bh;
    *(bf16x8*)&sBl[srow * 32 + sk] = bl;
    __syncthreads();
    bf16x8 fAh[2], fAl[2], fBh[2], fBl[2];
#pragma unroll
    for (int i = 0; i < 2; i++) {
      fAh[i] = *(const bf16x8*)&sAh[(wr * 32 + i * 16 + l16) * 32 + quad * 8];
      fAl[i] = *(const bf16x8*)&sAl[(wr * 32 + i * 16 + l16) * 32 + quad * 8];
      fBh[i] = *(const bf16x8*)&sBh[(wc * 32 + i * 16 + l16) * 32 + quad * 8];
      fBl[i] = *(const bf16x8*)&sBl[(wc * 32 + i * 16 + l16) * 32 + quad * 8];
    }
#pragma unroll
    for (int i = 0; i < 2; i++)
#pragma unroll
      for (int j = 0; j < 2; j++) {
        acc[i][j] = MFMA_BF16(fAh[i], fBh[j], acc[i][j], 0, 0, 0);
        acc[i][j] = MFMA_BF16(fAh[i], fBl[j], acc[i][j], 0, 0, 0);
        acc[i][j] = MFMA_BF16(fAl[i], fBh[j], acc[i][j], 0, 0, 0);
      }
  }
#pragma unroll
  for (int i = 0; i < 2; i++)
#pragma unroll
    for (int j = 0; j < 2; j++)
#pragma unroll
      for (int r = 0; r < 4; r++) {
        int row = wr * 32 + i * 16 + quad * 4 + r;
        int col = wc * 32 + j * 16 + l16;
        C[(size_t)(m0 + row) * Ndim + n0 + col] = acc[i][j][r];
      }
}

// ---------------------------------------------------------------- GRU step (r7 best)
// Grid (16 bt, 16 ct) — bt FAST so consecutively-dispatched blocks share the
// same Wp strip (per-XCD L2 locality). Tile: 64 b-rows x 96 permuted cols;
// wave tile 32x48; register-prefetch staging. Per-step launches: every
// cross-block sync variant measured 2-4x worse (r4/r8/r10/r12).
__global__ __launch_bounds__(256) void gru_step4(
    const bf16_t* __restrict__ Hh, const bf16_t* __restrict__ Hl,
    const bf16_t* __restrict__ Wph, const bf16_t* __restrict__ Wpl,
    const int* __restrict__ tok, const float* __restrict__ eg,
    const float* __restrict__ b_ih, const float* __restrict__ b_hh,
    bf16_t* __restrict__ Oh, bf16_t* __restrict__ Ol, int t) {
  __shared__ bf16_t sAh[64 * 32], sAl[64 * 32];
  __shared__ bf16_t sBh[96 * 32], sBl[96 * 32];
  __shared__ float sC[64 * 100];
  __shared__ float sbih[96], sbhh[96];
  const int tid = threadIdx.x;
  const int ct = blockIdx.y, m0 = blockIdx.x * 64;  // bt fast, ct slow
  const int n0q = ct * 96, n0e = ct * 32;
  const int wave = tid >> 6, lane = tid & 63;
  const int wr = wave >> 1, wc = wave & 1;
  const int quad = lane >> 4, l16 = lane & 15;
  const int srow = tid >> 2, sk = (tid & 3) * 8;
  const int b2row = 64 + ((tid & 127) >> 2);

  if (tid < 96) {
    sbih[tid] = b_ih[(tid >> 5) * 512 + n0e + (tid & 31)];
    sbhh[tid] = b_hh[(tid >> 5) * 512 + n0e + (tid & 31)];
  }

  float pir[8], piz[8], pin[8], phv[8];
#pragma unroll
  for (int u = 0; u < 8; u++) {
    int flat = u * 256 + tid;
    int row = flat >> 5, el = flat & 31;
    int bb = m0 + row, eG = n0e + el;
    int tk = tok[bb * T_ + t];
    pir[u] = eg[(size_t)tk * G3_ + eG];
    piz[u] = eg[(size_t)tk * G3_ + 512 + eG];
    pin[u] = eg[(size_t)tk * G3_ + 1024 + eG];
    size_t hidx = (size_t)bb * 512 + eG;
    phv[u] = (float)Hh[hidx] + (float)Hl[hidx];
  }

  f32x4 acc[2][3] = {};
  bf16x8 rah, ral, rbh0, rbl0, rbh1, rbl1;
  {
    size_t ao = (size_t)(m0 + srow) * 512 + sk;
    rah = *(const bf16x8*)&Hh[ao];
    ral = *(const bf16x8*)&Hl[ao];
    size_t bo = (size_t)(n0q + srow) * 512 + sk;
    rbh0 = *(const bf16x8*)&Wph[bo];
    rbl0 = *(const bf16x8*)&Wpl[bo];
    if (tid < 128) {
      size_t bo2 = (size_t)(n0q + b2row) * 512 + sk;
      rbh1 = *(const bf16x8*)&Wph[bo2];
      rbl1 = *(const bf16x8*)&Wpl[bo2];
    }
  }
#pragma unroll 1
  for (int kk = 0; kk < 16; ++kk) {
    __syncthreads();
    *(bf16x8*)&sAh[srow * 32 + sk] = rah;
    *(bf16x8*)&sAl[srow * 32 + sk] = ral;
    *(bf16x8*)&sBh[srow * 32 + sk] = rbh0;
    *(bf16x8*)&sBl[srow * 32 + sk] = rbl0;
    if (tid < 128) {
      *(bf16x8*)&sBh[b2row * 32 + sk] = rbh1;
      *(bf16x8*)&sBl[b2row * 32 + sk] = rbl1;
    }
    __syncthreads();
    if (kk < 15) {
      int k0 = (kk + 1) * 32;
      size_t ao = (size_t)(m0 + srow) * 512 + k0 + sk;
      rah = *(const bf16x8*)&Hh[ao];
      ral = *(const bf16x8*)&Hl[ao];
      size_t bo = (size_t)(n0q + srow) * 512 + k0 + sk;
      rbh0 = *(const bf16x8*)&Wph[bo];
      rbl0 = *(const bf16x8*)&Wpl[bo];
      if (tid < 128) {
        size_t bo2 = (size_t)(n0q + b2row) * 512 + k0 + sk;
        rbh1 = *(const bf16x8*)&Wph[bo2];
        rbl1 = *(const bf16x8*)&Wpl[bo2];
      }
    }
    bf16x8 fah[2], fal[2], fbh[3], fbl[3];
#pragma unroll
    for (int i = 0; i < 2; i++) {
      int off = (wr * 32 + i * 16 + l16) * 32 + quad * 8;
      fah[i] = *(const bf16x8*)&sAh[off];
      fal[i] = *(const bf16x8*)&sAl[off];
    }
#pragma unroll
    for (int j = 0; j < 3; j++) {
      int off = (wc * 48 + j * 16 + l16) * 32 + quad * 8;
      fbh[j] = *(const bf16x8*)&sBh[off];
      fbl[j] = *(const bf16x8*)&sBl[off];
    }
#pragma unroll
    for (int i = 0; i < 2; i++)
#pragma unroll
      for (int j = 0; j < 3; j++) {
        acc[i][j] = MFMA_BF16(fah[i], fbh[j], acc[i][j], 0, 0, 0);
        acc[i][j] = MFMA_BF16(fah[i], fbl[j], acc[i][j], 0, 0, 0);
        acc[i][j] = MFMA_BF16(fal[i], fbh[j], acc[i][j], 0, 0, 0);
      }
  }
  __syncthreads();
#pragma unroll
  for (int i = 0; i < 2; i++)
#pragma unroll
    for (int j = 0; j < 3; j++)
#pragma unroll
      for (int r = 0; r < 4; r++)
        sC[(wr * 32 + i * 16 + quad * 4 + r) * 100 + wc * 48 + j * 16 + l16] =
            acc[i][j][r];
  __syncthreads();
#pragma unroll
  for (int u = 0; u < 8; u++) {
    int flat = u * 256 + tid;
    int row = flat >> 5, el = flat & 31;
    int bb = m0 + row, eG = n0e + el;
    float ir = pir[u] + sbih[el];
    float iz = piz[u] + sbih[32 + el];
    float in_ = pin[u] + sbih[64 + el];
    float hr = sC[row * 100 + el] + sbhh[el];
    float hz = sC[row * 100 + 32 + el] + sbhh[32 + el];
    float hn = sC[row * 100 + 64 + el] + sbhh[64 + el];
    float r = 1.0f / (1.0f + __expf(-(ir + hr)));
    float z = 1.0f / (1.0f + __expf(-(iz + hz)));
    float targ = fminf(fmaxf(in_ + r * hn, -15.0f), 15.0f);
    float e2 = __expf(2.0f * targ);
    float n = (e2 - 1.0f) / (e2 + 1.0f);
    float hnew = (1.0f - z) * n + z * phv[u];
    size_t hidx = (size_t)bb * 512 + eG;
    bf16_t hh = (bf16_t)hnew;
    Oh[hidx] = hh;
    Ol[hidx] = (bf16_t)(hnew - (float)hh);
  }
}

// ---------------------------------------------------------------- MZI core (qc4, best)
__device__ inline void apply_u(float4 A, float4 Bv, float& x0r, float& x0i,
                               float& x1r, float& x1i) {
  float n0r = A.x * x0r - A.y * x0i + A.z * x1r - A.w * x1i;
  float n0i = A.x * x0i + A.y * x0r + A.z * x1i + A.w * x1r;
  float n1r = Bv.x * x0r - Bv.y * x0i + Bv.z * x1r - Bv.w * x1i;
  float n1i = Bv.x * x0i + Bv.y * x0r + Bv.z * x1i + Bv.w * x1r;
  x0r = n0r; x0i = n0i; x1r = n1r; x1i = n1i;
}

__global__ __launch_bounds__(256) void qc4(
    const float* __restrict__ zc, const float* __restrict__ bc,
    const float* __restrict__ Uep, const float* __restrict__ Uop,
    bf16_t* __restrict__ prh, bf16_t* __restrict__ prl,
    bf16_t* __restrict__ pih, bf16_t* __restrict__ pil) {
  __shared__ float sU[2][8192];
  const int tid = threadIdx.x;
  const int wave = tid >> 6, lane = tid & 63;
  const int b = blockIdx.x * 4 + wave;
  const int e0 = lane * 16;

#define STAGE_LAYER(l, buf)                                                  \
  {                                                                          \
    _Pragma("unroll") for (int r = 0; r < 4; r++) {                          \
      stage16f(&sU[buf][r * 1024 + wave * 256],                              \
               &Uep[(size_t)(l) * 4096 + r * 1024 + wave * 256 + lane * 4]); \
      stage16f(&sU[buf][4096 + r * 1024 + wave * 256],                       \
               &Uop[(size_t)(l) * 4096 + r * 1024 + wave * 256 + lane * 4]); \
    }                                                                        \
  }

  float xr[16], xi[16];
  {
    const float4* zr4 = (const float4*)&zc[(size_t)b * M2_ + e0];
    const float4* zi4 = (const float4*)&zc[(size_t)b * M2_ + M_ + e0];
    const float4* br4 = (const float4*)&bc[e0];
    const float4* bi4 = (const float4*)&bc[M_ + e0];
#pragma unroll
    for (int q = 0; q < 4; q++) {
      float4 a = zr4[q], bb = br4[q];
      xr[4 * q + 0] = a.x + bb.x; xr[4 * q + 1] = a.y + bb.y;
      xr[4 * q + 2] = a.z + bb.z; xr[4 * q + 3] = a.w + bb.w;
      float4 c = zi4[q], d = bi4[q];
      xi[4 * q + 0] = c.x + d.x; xi[4 * q + 1] = c.y + d.y;
      xi[4 * q + 2] = c.z + d.z; xi[4 * q + 3] = c.w + d.w;
    }
  }
  STAGE_LAYER(0, 0);
  {
    float s = 0.0f;
#pragma unroll
    for (int k = 0; k < 16; k++) s += xr[k] * xr[k] + xi[k] * xi[k];
    for (int off = 32; off; off >>= 1) s += __shfl_xor(s, off);
    float inv = 1.0f / sqrtf(s + 1e-8f);
#pragma unroll
    for (int k = 0; k < 16; k++) { xr[k] *= inv; xi[k] *= inv; }
  }
  __syncthreads();

#pragma unroll 1
  for (int l = 0; l < L_; ++l) {
    const int buf = l & 1;
    if (l + 1 < L_) STAGE_LAYER(l + 1, 1 - buf);
    const float* Ub = &sU[buf][0];
    const float* Ob = &sU[buf][4096];
    float4 eu[16];
#pragma unroll
    for (int j = 0; j < 16; j++) eu[j] = *(const float4*)&Ub[j * 256 + lane * 4];
#pragma unroll
    for (int j = 0; j < 8; j++)
      apply_u(eu[2 * j], eu[2 * j + 1], xr[2 * j], xi[2 * j], xr[2 * j + 1],
              xi[2 * j + 1]);
    float nr = __shfl_down(xr[0], 1);
    float ni = __shfl_down(xi[0], 1);
    float4 ou[16];
#pragma unroll
    for (int j = 0; j < 16; j++) ou[j] = *(const float4*)&Ob[j * 256 + lane * 4];
#pragma unroll
    for (int j = 0; j < 7; j++)
      apply_u(ou[2 * j], ou[2 * j + 1], xr[2 * j + 1], xi[2 * j + 1],
              xr[2 * j + 2], xi[2 * j + 2]);
    float sr_ = 0.0f, si_ = 0.0f;
    if (lane < 63) {
      float4 A = ou[14], Bv = ou[15];
      float n0r = A.x * xr[15] - A.y * xi[15] + A.z * nr - A.w * ni;
      float n0i = A.x * xi[15] + A.y * xr[15] + A.z * ni + A.w * nr;
      sr_ = Bv.x * xr[15] - Bv.y * xi[15] + Bv.z * nr - Bv.w * ni;
      si_ = Bv.x * xi[15] + Bv.y * xr[15] + Bv.z * ni + Bv.w * nr;
      xr[15] = n0r; xi[15] = n0i;
    }
    float rr = __shfl_up(sr_, 1);
    float ri2 = __shfl_up(si_, 1);
    if (lane > 0) { xr[0] = rr; xi[0] = ri2; }
    __syncthreads();
  }
#undef STAGE_LAYER
  size_t base = (size_t)b * M_ + e0;
#pragma unroll
  for (int half = 0; half < 2; half++) {
    bf16x8 vh, vl, wh, wl;
#pragma unroll
    for (int k = 0; k < 8; k++) {
      float vr = xr[half * 8 + k], vi = xi[half * 8 + k];
      bf16_t h1 = (bf16_t)vr;
      vh[k] = h1; vl[k] = (bf16_t)(vr - (float)h1);
      bf16_t h2 = (bf16_t)vi;
      wh[k] = h2; wl[k] = (bf16_t)(vi - (float)h2);
    }
    *(bf16x8*)&prh[base + half * 8] = vh;
    *(bf16x8*)&prl[base + half * 8] = vl;
    *(bf16x8*)&pih[base + half * 8] = wh;
    *(bf16x8*)&pil[base + half * 8] = wl;
  }
}

// ---------------------------------------------------------------- readout
__global__ __launch_bounds__(256) void readout_mfma(
    const bf16_t* __restrict__ Arh, const bf16_t* __restrict__ Arl,
    const bf16_t* __restrict__ Aih, const bf16_t* __restrict__ Ail,
    const bf16_t* __restrict__ Brh, const bf16_t* __restrict__ Brl,
    const bf16_t* __restrict__ Bih, const bf16_t* __restrict__ Bil,
    float* __restrict__ out) {
  __shared__ bf16_t sArh[64 * 32], sArl[64 * 32], sAih[64 * 32], sAil[64 * 32];
  __shared__ bf16_t sBrh[64 * 32], sBrl[64 * 32], sBih[64 * 32], sBil[64 * 32];
  const int tid = threadIdx.x;
  const int b0 = blockIdx.y * 64, v0 = blockIdx.x * 64;
  const int wave = tid >> 6, lane = tid & 63;
  const int wr = wave >> 1, wc = wave & 1;
  const int quad = lane >> 4, l16 = lane & 15;
  f32x4 aP[2][2] = {}, aQ[2][2] = {}, aI[2][2] = {};
  const int srow = tid >> 2, sk = (tid & 3) * 8;

  for (int k0 = 0; k0 < M_; k0 += 32) {
    size_t aoff = (size_t)(b0 + srow) * M_ + k0 + sk;
    size_t boff = (size_t)(v0 + srow) * M_ + k0 + sk;
    bf16x8 v0r = *(const bf16x8*)&Arh[aoff];
    bf16x8 v1r = *(const bf16x8*)&Arl[aoff];
    bf16x8 v2r = *(const bf16x8*)&Aih[aoff];
    bf16x8 v3r = *(const bf16x8*)&Ail[aoff];
    bf16x8 v4r = *(const bf16x8*)&Brh[boff];
    bf16x8 v5r = *(const bf16x8*)&Brl[boff];
    bf16x8 v6r = *(const bf16x8*)&Bih[boff];
    bf16x8 v7r = *(const bf16x8*)&Bil[boff];
    __syncthreads();
    *(bf16x8*)&sArh[srow * 32 + sk] = v0r;
    *(bf16x8*)&sArl[srow * 32 + sk] = v1r;
    *(bf16x8*)&sAih[srow * 32 + sk] = v2r;
    *(bf16x8*)&sAil[srow * 32 + sk] = v3r;
    *(bf16x8*)&sBrh[srow * 32 + sk] = v4r;
    *(bf16x8*)&sBrl[srow * 32 + sk] = v5r;
    *(bf16x8*)&sBih[srow * 32 + sk] = v6r;
    *(bf16x8*)&sBil[srow * 32 + sk] = v7r;
    __syncthreads();
    bf16x8 fArh[2], fArl[2], fAih[2], fAil[2], fBrh[2], fBrl[2], fBih[2], fBil[2];
#pragma unroll
    for (int i = 0; i < 2; i++) {
      int ra = (wr * 32 + i * 16 + l16) * 32 + quad * 8;
      int rb = (wc * 32 + i * 16 + l16) * 32 + quad * 8;
      fArh[i] = *(const bf16x8*)&sArh[ra];
      fArl[i] = *(const bf16x8*)&sArl[ra];
      fAih[i] = *(const bf16x8*)&sAih[ra];
      fAil[i] = *(const bf16x8*)&sAil[ra];
      fBrh[i] = *(const bf16x8*)&sBrh[rb];
      fBrl[i] = *(const bf16x8*)&sBrl[rb];
      fBih[i] = *(const bf16x8*)&sBih[rb];
      fBil[i] = *(const bf16x8*)&sBil[rb];
    }
#pragma unroll
    for (int i = 0; i < 2; i++)
#pragma unroll
      for (int j = 0; j < 2; j++) {
        aP[i][j] = MFMA_BF16(fArh[i], fBrh[j], aP[i][j], 0, 0, 0);
        aP[i][j] = MFMA_BF16(fArh[i], fBrl[j], aP[i][j], 0, 0, 0);
        aP[i][j] = MFMA_BF16(fArl[i], fBrh[j], aP[i][j], 0, 0, 0);
        aQ[i][j] = MFMA_BF16(fAih[i], fBih[j], aQ[i][j], 0, 0, 0);
        aQ[i][j] = MFMA_BF16(fAih[i], fBil[j], aQ[i][j], 0, 0, 0);
        aQ[i][j] = MFMA_BF16(fAil[i], fBih[j], aQ[i][j], 0, 0, 0);
        aI[i][j] = MFMA_BF16(fArh[i], fBih[j], aI[i][j], 0, 0, 0);
        aI[i][j] = MFMA_BF16(fArh[i], fBil[j], aI[i][j], 0, 0, 0);
        aI[i][j] = MFMA_BF16(fArl[i], fBih[j], aI[i][j], 0, 0, 0);
        aI[i][j] = MFMA_BF16(fAih[i], fBrh[j], aI[i][j], 0, 0, 0);
        aI[i][j] = MFMA_BF16(fAih[i], fBrl[j], aI[i][j], 0, 0, 0);
        aI[i][j] = MFMA_BF16(fAil[i], fBrh[j], aI[i][j], 0, 0, 0);
      }
  }
#pragma unroll
  for (int i = 0; i < 2; i++)
#pragma unroll
    for (int j = 0; j < 2; j++)
#pragma unroll
      for (int r = 0; r < 4; r++) {
        int row = wr * 32 + i * 16 + quad * 4 + r;
        int col = wc * 32 + j * 16 + l16;
        float re = aP[i][j][r] - aQ[i][j][r];
        float im = aI[i][j][r];
        out[(size_t)(b0 + row) * V_ + v0 + col] = logf(re * re + im * im + 1e-12f);
      }
}

// ---------------------------------------------------------------- logsumexp
__global__ __launch_bounds__(256) void lse_kernel(float* __restrict__ out) {
  __shared__ float redm[4], reds[4];
  const int b = blockIdx.x, t = threadIdx.x;
  float4 v = *(float4*)&out[(size_t)b * V_ + 4 * t];
  float mx = fmaxf(fmaxf(v.x, v.y), fmaxf(v.z, v.w));
  for (int off = 32; off; off >>= 1) mx = fmaxf(mx, __shfl_down(mx, off, 64));
  if ((t & 63) == 0) redm[t >> 6] = mx;
  __syncthreads();
  mx = fmaxf(fmaxf(redm[0], redm[1]), fmaxf(redm[2], redm[3]));
  float s = expf(v.x - mx) + expf(v.y - mx) + expf(v.z - mx) + expf(v.w - mx);
  for (int off = 32; off; off >>= 1) s += __shfl_down(s, off, 64);
  if ((t & 63) == 0) reds[t >> 6] = s;
  __syncthreads();
  s = reds[0] + reds[1] + reds[2] + reds[3];
  float lse = mx + logf(s);
  v.x -= lse; v.y -= lse; v.z -= lse; v.w -= lse;
  *(float4*)&out[(size_t)b * V_ + 4 * t] = v;
}

// ---------------------------------------------------------------- launch
extern "C" void kernel_launch(void* const* d_in, const int* in_sizes, int n_in,
                              void* d_out, int out_size, void* d_ws, size_t ws_size,
                              hipStream_t stream) {
  const int*   tokens = (const int*)d_in[0];
  const float* embed  = (const float*)d_in[1];
  const float* W_ih   = (const float*)d_in[2];
  const float* W_hh   = (const float*)d_in[3];
  const float* b_ih   = (const float*)d_in[4];
  const float* b_hh   = (const float*)d_in[5];
  const float* Wc     = (const float*)d_in[6];
  const float* bc     = (const float*)d_in[7];
  const float* phase  = (const float*)d_in[8];
  const float* theta_e = (const float*)d_in[9];
  const float* phi_e  = (const float*)d_in[10];
  const float* rho_e  = (const float*)d_in[11];
  const float* theta_o = (const float*)d_in[12];
  const float* phi_o  = (const float*)d_in[13];
  const float* rho_o  = (const float*)d_in[14];
  const float* R_real = (const float*)d_in[15];
  const float* R_imag = (const float*)d_in[16];
  float* out = (float*)d_out;

  char* w = (char*)d_ws;
  auto alloc = [&](size_t bytes) -> void* {
    void* p = (void*)w;
    w += (bytes + 255) & ~(size_t)255;
    return p;
  };
  // region0: weight splits; later aliased by psi hi/lo (dead by then)
  char* region0 = w;
  bf16_t* emb_hi = (bf16_t*)alloc((size_t)V_ * E_ * 2);
  bf16_t* emb_lo = (bf16_t*)alloc((size_t)V_ * E_ * 2);
  bf16_t* wih_hi = (bf16_t*)alloc((size_t)G3_ * E_ * 2);
  bf16_t* wih_lo = (bf16_t*)alloc((size_t)G3_ * E_ * 2);
  bf16_t* wc_hi  = (bf16_t*)alloc((size_t)M2_ * E_ * 2);
  bf16_t* wc_lo  = (bf16_t*)alloc((size_t)M2_ * E_ * 2);
  // region1: eg + Wp; later aliased by zc
  char* region1 = w;
  float*  eg     = (float*)alloc((size_t)V_ * G3_ * 4);
  bf16_t* Wp_hi  = (bf16_t*)alloc((size_t)G3_ * E_ * 2);
  bf16_t* Wp_lo  = (bf16_t*)alloc((size_t)G3_ * E_ * 2);
  // persistent
  bf16_t* h0_hi = (bf16_t*)alloc((size_t)B_ * E_ * 2);
  bf16_t* h0_lo = (bf16_t*)alloc((size_t)B_ * E_ * 2);
  bf16_t* h1_hi = (bf16_t*)alloc((size_t)B_ * E_ * 2);
  bf16_t* h1_lo = (bf16_t*)alloc((size_t)B_ * E_ * 2);
  bf16_t* rr_hi = (bf16_t*)alloc((size_t)V_ * M_ * 2);
  bf16_t* rr_lo = (bf16_t*)alloc((size_t)V_ * M_ * 2);
  bf16_t* ri_hi = (bf16_t*)alloc((size_t)V_ * M_ * 2);
  bf16_t* ri_lo = (bf16_t*)alloc((size_t)V_ * M_ * 2);
  float*  Uep   = (float*)alloc((size_t)L_ * 4096 * 4);
  float*  Uop   = (float*)alloc((size_t)L_ * 4096 * 4);

  // aliases
  float*  zc  = (float*)region1;
  bf16_t* prh = (bf16_t*)(region0 + 0 * 2097152);
  bf16_t* prl = (bf16_t*)(region0 + 1 * 2097152);
  bf16_t* pih = (bf16_t*)(region0 + 2 * 2097152);
  bf16_t* pil = (bf16_t*)(region0 + 3 * 2097152);

  hipMemsetAsync(h0_hi, 0, (size_t)B_ * E_ * 2 * 2, stream);

  // ONE fused prep launch
  prep_all<<<6016, 256, 0, stream>>>(
      embed, emb_hi, emb_lo, W_ih, wih_hi, wih_lo, Wc, wc_hi, wc_lo, R_real,
      rr_hi, rr_lo, R_imag, ri_hi, ri_lo, W_hh, Wp_hi, Wp_lo, phase, theta_e,
      phi_e, rho_e, Uep, theta_o, phi_o, rho_o, Uop);

  // eg = embed @ W_ih^T  (V x 3E)
  {
    dim3 grid(G3_ / 64, V_ / 64);
    gemm_bt_mfma_split<<<grid, 256, 0, stream>>>(emb_hi, emb_lo, wih_hi, wih_lo,
                                                 eg, G3_, E_);
  }

  // GRU: 64 per-step launches (measured optimum across all 5 structures)
  for (int t = 0; t < T_; ++t) {
    const bf16_t* ih = (t & 1) ? h1_hi : h0_hi;
    const bf16_t* il = (t & 1) ? h1_lo : h0_lo;
    bf16_t* oh = (t & 1) ? h0_hi : h1_hi;
    bf16_t* ol = (t & 1) ? h0_lo : h1_lo;
    dim3 grid(16, 16);  // bt fast, ct slow (L2 locality)
    gru_step4<<<grid, 256, 0, stream>>>(ih, il, Wp_hi, Wp_lo, tokens, eg, b_ih,
                                        b_hh, oh, ol, t);
  }

  // zc = h @ Wc^T  (B x 2M); final h in buffer 0 after t=63
  {
    dim3 grid(M2_ / 64, B_ / 64);
    gemm_bt_mfma_split<<<grid, 256, 0, stream>>>(h0_hi, h0_lo, wc_hi, wc_lo,
                                                 zc, M2_, E_);
  }

  // MZI stack (qc4: dbuf LDS tables — best measured)
  qc4<<<B_ / 4, 256, 0, stream>>>(zc, bc, Uep, Uop, prh, prl, pih, pil);

  // readout
  {
    dim3 grid(V_ / 64, B_ / 64);
    readout_mfma<<<grid, 256, 0, stream>>>(prh, prl, pih, pil, rr_hi, rr_lo,
                                           ri_hi, ri_lo, out);
  }

  // logsumexp
  lse_kernel<<<B_, 256, 0, stream>>>(out);
}